// Round 7
// baseline (137.416 us; speedup 1.0000x reference)
//
#include <hip/hip_runtime.h>

#define IN_DIM 128
#define OUT_DIM 32
#define DEG 16
#define EPS 1e-8f

typedef __attribute__((ext_vector_type(8))) short bf16x8;
typedef __attribute__((ext_vector_type(4))) float f32x4;

// ds_swizzle xor-mask patterns (BitMode: (xor<<10)|0x1F), 32-lane domain
#define SWZ(x, p) __int_as_float(__builtin_amdgcn_ds_swizzle(__float_as_int(x), (p)))

static __device__ __forceinline__ unsigned short f2bf(float x) {  // RNE f32->bf16
  unsigned u = __float_as_uint(x);
  u += 0x7FFFu + ((u >> 16) & 1u);
  return (unsigned short)(u >> 16);
}
static __device__ __forceinline__ float bflo(unsigned u) { return __uint_as_float(u << 16); }
static __device__ __forceinline__ float bfhi(unsigned u) { return __uint_as_float(u & 0xFFFF0000u); }

static __device__ __forceinline__ bf16x8 pack8(float4 a, float4 b) {
  bf16x8 r;
  r[0] = (short)f2bf(a.x); r[1] = (short)f2bf(a.y);
  r[2] = (short)f2bf(a.z); r[3] = (short)f2bf(a.w);
  r[4] = (short)f2bf(b.x); r[5] = (short)f2bf(b.y);
  r[6] = (short)f2bf(b.z); r[7] = (short)f2bf(b.w);
  return r;
}

// Kernel 1 (MFMA): zh = normalize(h @ W^T) rows stored bf16; nrm = true f32
// row norms. Block = 4 waves = 32 nodes (N=100000 -> 3125 blocks, no tail).
// Wave (ng=w>>1, oh=w&1): nodes [mb,mb+16) x outs [16*oh,+16),
// mfma_f32_16x16x32_bf16, K=128 in 4 chunks. No scalar loads / no LDS in the
// K-chunk path (R5 lesson: s_load+ds_read mixing serializes on lgkmcnt).
__global__ __launch_bounds__(256) void gemm_norm_kernel(
    const float* __restrict__ h, const float* __restrict__ W,
    unsigned short* __restrict__ zhb, float* __restrict__ nrm, int N) {
  __shared__ float pss[2][32];

  const int tid = threadIdx.x;
  const int wv = tid >> 6;
  const int l = tid & 63;
  const int n16 = l & 15;  // A row (node) / B col (out) lane index
  const int q = l >> 4;    // quad
  const int ng = wv >> 1, oh = wv & 1;
  const int mb = blockIdx.x * 32 + ng * 16;

  // B fragments (W = 16 KB, L1/L2-hot; redundant per-wave reads are cheap)
  bf16x8 bfr[4];
  {
    const float* wr = W + (size_t)(oh * 16 + n16) * IN_DIM + q * 8;
#pragma unroll
    for (int c = 0; c < 4; ++c) {
      const float4 w0 = *(const float4*)(wr + c * 32);
      const float4 w1 = *(const float4*)(wr + c * 32 + 4);
      bfr[c] = pack8(w0, w1);
    }
  }
  // A fragments
  int m = mb + n16;
  if (m >= N) m = N - 1;  // clamped read; stores guarded
  bf16x8 afr[4];
  {
    const float* hr = h + (size_t)m * IN_DIM + q * 8;
#pragma unroll
    for (int c = 0; c < 4; ++c) {
      const float4 a0 = *(const float4*)(hr + c * 32);
      const float4 a1 = *(const float4*)(hr + c * 32 + 4);
      afr[c] = pack8(a0, a1);
    }
  }

  f32x4 acc = {0.f, 0.f, 0.f, 0.f};
#pragma unroll
  for (int c = 0; c < 4; ++c)
    acc = __builtin_amdgcn_mfma_f32_16x16x32_bf16(afr[c], bfr[c], acc, 0, 0, 0);
  // C/D: col(out) = n16, row(node-in-group) = q*4 + r

  // per-node sum of squares over this wave's 16 cols: butterfly over n16
#pragma unroll
  for (int r = 0; r < 4; ++r) {
    float s = acc[r] * acc[r];
    s += SWZ(s, 0x041F);
    s += SWZ(s, 0x081F);
    s += SWZ(s, 0x101F);
    s += SWZ(s, 0x201F);  // sum over 16 cols, all lanes
    if (n16 == 0) pss[oh][ng * 16 + q * 4 + r] = s;
  }
  __syncthreads();

  // combine halves -> inv per row-node, scale, pack pairs, store
#pragma unroll
  for (int r = 0; r < 4; ++r) {
    const int idx = ng * 16 + q * 4 + r;          // node within tile
    const float ss = pss[0][idx] + pss[1][idx];   // broadcast LDS reads
    const float inv = 1.0f / fmaxf(sqrtf(ss), EPS);
    const float zn = acc[r] * inv;
    const float partner = SWZ(zn, 0x041F);        // col n16^1, same node
    const int node = mb + q * 4 + r;
    if (((n16 & 1) == 0) && node < N) {
      const unsigned pk = (unsigned)f2bf(zn) | ((unsigned)f2bf(partner) << 16);
      *(unsigned*)(zhb + (size_t)node * OUT_DIM + oh * 16 + n16) = pk;
    }
  }
  if (tid < 32) {
    const int node = blockIdx.x * 32 + tid;
    if (node < N) nrm[node] = sqrtf(pss[0][tid] + pss[1][tid]);
  }
}

// Kernel 2: wave = 2 nodes (one per half-wave), lane l5 = (edge e=l5>>1,
// chunk c=l5&1 of 16 outs). 18.4 KB LDS -> 8 blocks/CU = 32 waves/CU (R6
// lesson: this kernel is latency-bound and needs TLP, not per-wave ILP).
// zh rows are pre-normalized -> cos = raw dot, no inv_norm gathers at all.
// Dot: 16 fma + 1 swizzle; denom: 4 swizzles; edge->out transpose via
// private per-node LDS slot (same-wave RAW, no barrier).
// Scores beta*(cos-1) bounded in [-2b,0] -> no softmax max pass.
__global__ __launch_bounds__(256) void edge_kernel(
    const unsigned short* __restrict__ zhb, const float* __restrict__ nrm,
    const int* __restrict__ src, const float* __restrict__ beta_p,
    float* __restrict__ out, int N) {
  __shared__ float xp[8 * DEG * 36];  // 8 node-slots x 16e x stride36 = 18.4 KB

  const int tid = threadIdx.x;
  const int l5 = tid & 31, half = (tid >> 5) & 1, wv = tid >> 6;
  const int gw = blockIdx.x * 4 + wv;
  if (gw * 2 >= N) return;             // wave-uniform exit
  const int n = gw * 2 + half;
  const int ne = (n < N) ? n : N - 1;  // clamp loads; store guarded
  const int e = l5 >> 1, c = l5 & 1;

  const float beta = *beta_p;
  const int se = src[(size_t)ne * DEG + e];  // pair-dup, coalesced
  const float nrm_s = nrm[se];               // only norm gather needed

  const uint4* zs4 = (const uint4*)(zhb + (size_t)se * OUT_DIM) + c * 2;
  const uint4 sa = zs4[0], sb = zs4[1];      // 16 bf16 of src row chunk c
  const uint4* zd4 = (const uint4*)(zhb + (size_t)ne * OUT_DIM) + c * 2;
  const uint4 da = zd4[0], db = zd4[1];      // 16 bf16 of dst row chunk c

  float vs[16];
  vs[0] = bflo(sa.x);  vs[1] = bfhi(sa.x);  vs[2] = bflo(sa.y);  vs[3] = bfhi(sa.y);
  vs[4] = bflo(sa.z);  vs[5] = bfhi(sa.z);  vs[6] = bflo(sa.w);  vs[7] = bfhi(sa.w);
  vs[8] = bflo(sb.x);  vs[9] = bfhi(sb.x);  vs[10] = bflo(sb.y); vs[11] = bfhi(sb.y);
  vs[12] = bflo(sb.z); vs[13] = bfhi(sb.z); vs[14] = bflo(sb.w); vs[15] = bfhi(sb.w);
  float vd[16];
  vd[0] = bflo(da.x);  vd[1] = bfhi(da.x);  vd[2] = bflo(da.y);  vd[3] = bfhi(da.y);
  vd[4] = bflo(da.z);  vd[5] = bfhi(da.z);  vd[6] = bflo(da.w);  vd[7] = bfhi(da.w);
  vd[8] = bflo(db.x);  vd[9] = bfhi(db.x);  vd[10] = bflo(db.y); vd[11] = bfhi(db.y);
  vd[12] = bflo(db.z); vd[13] = bfhi(db.z); vd[14] = bflo(db.w); vd[15] = bfhi(db.w);

  float pr = vs[0] * vd[0];
#pragma unroll
  for (int i = 1; i < 16; ++i) pr = fmaf(vs[i], vd[i], pr);
  pr += SWZ(pr, 0x041F);  // xor1: other 16-chunk -> full dot = cos (normalized rows)

  const float ex = __expf(beta * (pr - 1.0f));

  float den = ex;
  den += SWZ(den, 0x081F);
  den += SWZ(den, 0x101F);
  den += SWZ(den, 0x201F);
  den += SWZ(den, 0x401F);  // sum over 16 edges
  const float rd = 1.0f / den;

  const float sc = ex * nrm_s;  // weight x un-normalization of zhat_s
  float* slot = xp + (wv * 2 + half) * (DEG * 36);
  float4* wp = (float4*)(slot + e * 36 + c * 16);
  wp[0] = make_float4(sc * vs[0], sc * vs[1], sc * vs[2], sc * vs[3]);
  wp[1] = make_float4(sc * vs[4], sc * vs[5], sc * vs[6], sc * vs[7]);
  wp[2] = make_float4(sc * vs[8], sc * vs[9], sc * vs[10], sc * vs[11]);
  wp[3] = make_float4(sc * vs[12], sc * vs[13], sc * vs[14], sc * vs[15]);
  // same-wave LDS RAW: compiler inserts lgkmcnt wait; no barrier

  float s = 0.f;
#pragma unroll
  for (int e2 = 0; e2 < DEG; ++e2)
    s += slot[e2 * 36 + l5];  // bank (4e2+l5)%32: conflict-free reads

  if (n < N) out[(size_t)n * OUT_DIM + l5] = s * rd;  // coalesced 128B/node
}

extern "C" void kernel_launch(void* const* d_in, const int* in_sizes, int n_in,
                              void* d_out, int out_size, void* d_ws, size_t ws_size,
                              hipStream_t stream) {
  const float* h    = (const float*)d_in[0];
  const float* W    = (const float*)d_in[1];
  const float* beta = (const float*)d_in[2];
  const int*   src  = (const int*)d_in[3];
  // d_in[4] = dst == arange(E)//DEG -> node n owns edges [n*DEG, (n+1)*DEG)

  const int N = in_sizes[0] / IN_DIM;

  unsigned short* zhb = (unsigned short*)d_ws;       // N*32 bf16 = 6.4 MB (normalized)
  float* nrm = (float*)(zhb + (size_t)N * OUT_DIM);  // N floats (true norms)

  const int bl1 = (N + 31) / 32;  // 32 nodes per block
  gemm_norm_kernel<<<bl1, 256, 0, stream>>>(h, W, zhb, nrm, N);

  const int bl2 = (N + 7) / 8;    // 8 nodes per block (4 waves x 2 nodes)
  edge_kernel<<<bl2, 256, 0, stream>>>(zhb, nrm, src, beta, (float*)d_out, N);
}

// Round 8
// 132.911 us; speedup vs baseline: 1.0339x; 1.0339x over previous
//
#include <hip/hip_runtime.h>

#define IN_DIM 128
#define OUT_DIM 32
#define DEG 16
#define EPS 1e-8f

typedef __attribute__((ext_vector_type(8))) short bf16x8;
typedef __attribute__((ext_vector_type(4))) float f32x4;

// ds_swizzle xor-mask patterns (BitMode: (xor<<10)|0x1F), 32-lane domain
#define SWZ(x, p) __int_as_float(__builtin_amdgcn_ds_swizzle(__float_as_int(x), (p)))

static __device__ __forceinline__ unsigned short f2bf(float x) {  // RNE f32->bf16
  unsigned u = __float_as_uint(x);
  u += 0x7FFFu + ((u >> 16) & 1u);
  return (unsigned short)(u >> 16);
}
static __device__ __forceinline__ float bflo(unsigned u) { return __uint_as_float(u << 16); }
static __device__ __forceinline__ float bfhi(unsigned u) { return __uint_as_float(u & 0xFFFF0000u); }

static __device__ __forceinline__ bf16x8 pack8(float4 a, float4 b) {
  bf16x8 r;
  r[0] = (short)f2bf(a.x); r[1] = (short)f2bf(a.y);
  r[2] = (short)f2bf(a.z); r[3] = (short)f2bf(a.w);
  r[4] = (short)f2bf(b.x); r[5] = (short)f2bf(b.y);
  r[6] = (short)f2bf(b.z); r[7] = (short)f2bf(b.w);
  return r;
}

// Kernel 1 (MFMA, full-width wave): zh = normalize(h @ W^T) rows (bf16),
// nrm = true f32 row norms. ONE wave computes 16 nodes x ALL 32 outs
// (two B-frag halves, 8 MFMA): h rows are read exactly ONCE (R7 version
// read them twice, once per output-half wave), and the norm reduction is a
// pure 4-swizzle butterfly -- zero LDS, zero __syncthreads in this kernel.
__global__ __launch_bounds__(256) void gemm_norm_kernel(
    const float* __restrict__ h, const float* __restrict__ W,
    unsigned short* __restrict__ zhb, float* __restrict__ nrm, int N) {
  const int tid = threadIdx.x;
  const int wv = tid >> 6;
  const int l = tid & 63;
  const int n16 = l & 15;  // A row (node) / B col (out) lane index
  const int q = l >> 4;    // quad
  const int mb = (blockIdx.x * 4 + wv) * 16;  // 16 nodes per wave
  if (mb >= N) return;     // wave-uniform exit (tail waves)

  // B fragments, both output halves (W = 16 KB, L1/L2-hot)
  bf16x8 bfr[2][4];
#pragma unroll
  for (int oh = 0; oh < 2; ++oh) {
    const float* wr = W + (size_t)(oh * 16 + n16) * IN_DIM + q * 8;
#pragma unroll
    for (int c = 0; c < 4; ++c)
      bfr[oh][c] = pack8(*(const float4*)(wr + c * 32),
                         *(const float4*)(wr + c * 32 + 4));
  }
  // A fragments (16 h rows, read once)
  int m = mb + n16;
  if (m >= N) m = N - 1;  // clamped read; stores guarded
  bf16x8 afr[4];
  {
    const float* hr = h + (size_t)m * IN_DIM + q * 8;
#pragma unroll
    for (int c = 0; c < 4; ++c)
      afr[c] = pack8(*(const float4*)(hr + c * 32),
                     *(const float4*)(hr + c * 32 + 4));
  }

  f32x4 acc0 = {0.f, 0.f, 0.f, 0.f}, acc1 = {0.f, 0.f, 0.f, 0.f};
#pragma unroll
  for (int c = 0; c < 4; ++c) {
    acc0 = __builtin_amdgcn_mfma_f32_16x16x32_bf16(afr[c], bfr[0][c], acc0, 0, 0, 0);
    acc1 = __builtin_amdgcn_mfma_f32_16x16x32_bf16(afr[c], bfr[1][c], acc1, 0, 0, 0);
  }
  // C/D: col(out) = n16 (+16 for acc1), row(node) = q*4 + r

#pragma unroll
  for (int r = 0; r < 4; ++r) {
    // full 32-col sum of squares for node q*4+r: butterfly over n16 lanes
    float s = acc0[r] * acc0[r] + acc1[r] * acc1[r];
    s += SWZ(s, 0x041F);
    s += SWZ(s, 0x081F);
    s += SWZ(s, 0x101F);
    s += SWZ(s, 0x201F);  // sum over the 16 n16-lanes, all lanes hold it
    const float ns = sqrtf(s);
    const float inv = 1.0f / fmaxf(ns, EPS);
    const float z0 = acc0[r] * inv, z1 = acc1[r] * inv;
    const float p0 = SWZ(z0, 0x041F), p1 = SWZ(z1, 0x041F);  // col n16^1
    const int node = mb + q * 4 + r;
    if (((n16 & 1) == 0) && node < N) {
      unsigned short* zr = zhb + (size_t)node * OUT_DIM;
      *(unsigned*)(zr + n16) =
          (unsigned)f2bf(z0) | ((unsigned)f2bf(p0) << 16);
      *(unsigned*)(zr + 16 + n16) =
          (unsigned)f2bf(z1) | ((unsigned)f2bf(p1) << 16);
    }
    if (n16 == 0 && node < N) nrm[node] = ns;
  }
}

// Kernel 2 (unchanged from R7): wave = 2 nodes, lane l5 = (edge e=l5>>1,
// chunk c=l5&1 of 16 outs). 18.4 KB LDS -> 8 blocks/CU = 32 waves/CU.
// zh rows pre-normalized -> cos = raw dot. Dot: 16 fma + 1 swizzle; denom:
// 4 swizzles; edge->out transpose via private per-node LDS slot (same-wave
// RAW, no barrier). beta*(cos-1) in [-2b,0] -> no softmax max pass.
__global__ __launch_bounds__(256) void edge_kernel(
    const unsigned short* __restrict__ zhb, const float* __restrict__ nrm,
    const int* __restrict__ src, const float* __restrict__ beta_p,
    float* __restrict__ out, int N) {
  __shared__ float xp[8 * DEG * 36];  // 8 node-slots x 16e x stride36 = 18.4 KB

  const int tid = threadIdx.x;
  const int l5 = tid & 31, half = (tid >> 5) & 1, wv = tid >> 6;
  const int gw = blockIdx.x * 4 + wv;
  if (gw * 2 >= N) return;             // wave-uniform exit
  const int n = gw * 2 + half;
  const int ne = (n < N) ? n : N - 1;  // clamp loads; store guarded
  const int e = l5 >> 1, c = l5 & 1;

  const float beta = *beta_p;
  const int se = src[(size_t)ne * DEG + e];  // pair-dup, coalesced
  const float nrm_s = nrm[se];               // only norm gather needed

  const uint4* zs4 = (const uint4*)(zhb + (size_t)se * OUT_DIM) + c * 2;
  const uint4 sa = zs4[0], sb = zs4[1];      // 16 bf16 of src row chunk c
  const uint4* zd4 = (const uint4*)(zhb + (size_t)ne * OUT_DIM) + c * 2;
  const uint4 da = zd4[0], db = zd4[1];      // 16 bf16 of dst row chunk c

  float vs[16];
  vs[0] = bflo(sa.x);  vs[1] = bfhi(sa.x);  vs[2] = bflo(sa.y);  vs[3] = bfhi(sa.y);
  vs[4] = bflo(sa.z);  vs[5] = bfhi(sa.z);  vs[6] = bflo(sa.w);  vs[7] = bfhi(sa.w);
  vs[8] = bflo(sb.x);  vs[9] = bfhi(sb.x);  vs[10] = bflo(sb.y); vs[11] = bfhi(sb.y);
  vs[12] = bflo(sb.z); vs[13] = bfhi(sb.z); vs[14] = bflo(sb.w); vs[15] = bfhi(sb.w);
  float vd[16];
  vd[0] = bflo(da.x);  vd[1] = bfhi(da.x);  vd[2] = bflo(da.y);  vd[3] = bfhi(da.y);
  vd[4] = bflo(da.z);  vd[5] = bfhi(da.z);  vd[6] = bflo(da.w);  vd[7] = bfhi(da.w);
  vd[8] = bflo(db.x);  vd[9] = bfhi(db.x);  vd[10] = bflo(db.y); vd[11] = bfhi(db.y);
  vd[12] = bflo(db.z); vd[13] = bfhi(db.z); vd[14] = bflo(db.w); vd[15] = bfhi(db.w);

  float pr = vs[0] * vd[0];
#pragma unroll
  for (int i = 1; i < 16; ++i) pr = fmaf(vs[i], vd[i], pr);
  pr += SWZ(pr, 0x041F);  // xor1: other 16-chunk -> full dot = cos

  const float ex = __expf(beta * (pr - 1.0f));

  float den = ex;
  den += SWZ(den, 0x081F);
  den += SWZ(den, 0x101F);
  den += SWZ(den, 0x201F);
  den += SWZ(den, 0x401F);  // sum over 16 edges
  const float rd = 1.0f / den;

  const float sc = ex * nrm_s;  // weight x un-normalization of zhat_s
  float* slot = xp + (wv * 2 + half) * (DEG * 36);
  float4* wp = (float4*)(slot + e * 36 + c * 16);
  wp[0] = make_float4(sc * vs[0], sc * vs[1], sc * vs[2], sc * vs[3]);
  wp[1] = make_float4(sc * vs[4], sc * vs[5], sc * vs[6], sc * vs[7]);
  wp[2] = make_float4(sc * vs[8], sc * vs[9], sc * vs[10], sc * vs[11]);
  wp[3] = make_float4(sc * vs[12], sc * vs[13], sc * vs[14], sc * vs[15]);
  // same-wave LDS RAW: compiler inserts lgkmcnt wait; no barrier

  float s = 0.f;
#pragma unroll
  for (int e2 = 0; e2 < DEG; ++e2)
    s += slot[e2 * 36 + l5];  // bank (4e2+l5)%32: conflict-free reads

  if (n < N) out[(size_t)n * OUT_DIM + l5] = s * rd;  // coalesced 128B/node
}

extern "C" void kernel_launch(void* const* d_in, const int* in_sizes, int n_in,
                              void* d_out, int out_size, void* d_ws, size_t ws_size,
                              hipStream_t stream) {
  const float* h    = (const float*)d_in[0];
  const float* W    = (const float*)d_in[1];
  const float* beta = (const float*)d_in[2];
  const int*   src  = (const int*)d_in[3];
  // d_in[4] = dst == arange(E)//DEG -> node n owns edges [n*DEG, (n+1)*DEG)

  const int N = in_sizes[0] / IN_DIM;

  unsigned short* zhb = (unsigned short*)d_ws;       // N*32 bf16 = 6.4 MB (normalized)
  float* nrm = (float*)(zhb + (size_t)N * OUT_DIM);  // N floats (true norms)

  const int bl1 = (N + 63) / 64;  // 64 nodes per block (4 waves x 16 nodes)
  gemm_norm_kernel<<<bl1, 256, 0, stream>>>(h, W, zhb, nrm, N);

  const int bl2 = (N + 7) / 8;    // 8 nodes per block (4 waves x 2 nodes)
  edge_kernel<<<bl2, 256, 0, stream>>>(zhb, nrm, src, beta, (float*)d_out, N);
}